// Round 10
// baseline (2198.443 us; speedup 1.0000x reference)
//
#include <hip/hip_runtime.h>

#define B_ 256
#define T_ 256
#define E_ 512
#define U_ 1024
#define G_ 4096   // 4*U
#define V_ 50000
#define TC_ 32    // timesteps per x_proj chunk
#define NCH_ 8    // T_/TC_
#define NG_ 8     // scan groups
#define NS_ 32    // slots (blocks) per group

typedef __bf16 bf16x8 __attribute__((ext_vector_type(8)));
typedef float f32x4 __attribute__((ext_vector_type(4)));
typedef unsigned short us8 __attribute__((ext_vector_type(8)));

__device__ __forceinline__ unsigned short f2bf(float f) {
  union { float f; unsigned u; } v; v.f = f;
  unsigned u = v.u;
  u = (u + 0x7FFFu + ((u >> 16) & 1u)) >> 16;   // RNE
  return (unsigned short)u;
}
__device__ __forceinline__ float bf2f(unsigned short h) {
  union { unsigned u; float f; } v; v.u = ((unsigned)h) << 16;
  return v.f;
}
__device__ __forceinline__ float sigm_(float x) { return 1.f / (1.f + __expf(-x)); }
__device__ __forceinline__ float tanh_(float x) { return 2.f / (1.f + __expf(-2.f * x)) - 1.f; }

__device__ __forceinline__ void gload16(const void* g, void* l) {
  __builtin_amdgcn_global_load_lds((const __attribute__((address_space(1))) void*)g,
                                   (__attribute__((address_space(3))) void*)l, 16, 0, 0);
}
// sc0 variant on the LDS-DMA path (R6-proven)
__device__ __forceinline__ void gload16c(const void* g, void* l) {
  __builtin_amdgcn_global_load_lds((const __attribute__((address_space(1))) void*)g,
                                   (__attribute__((address_space(3))) void*)l, 16, 0, 1);
}

// packed column p = s*128 + gg*32 + ul  ->  original gate column gg*1024 + s*32 + ul
__device__ __forceinline__ int orig_col3(int p) {
  return (((p >> 5) & 3) << 10) + ((p >> 7) << 5) + (p & 31);
}

// ---------------- prep: f32 -> bf16 (row-major) ----------------
__global__ void cvt_bf16_kernel(const float* __restrict__ in, unsigned short* __restrict__ out, long n) {
  long i = (((long)blockIdx.x * blockDim.x) + threadIdx.x) << 3;
  long stride = ((long)gridDim.x * blockDim.x) << 3;
  for (; i < n; i += stride) {
    float4 x = *(const float4*)(in + i);
    float4 y = *(const float4*)(in + i + 4);
    us8 v;
    v[0] = f2bf(x.x); v[1] = f2bf(x.y); v[2] = f2bf(x.z); v[3] = f2bf(x.w);
    v[4] = f2bf(y.x); v[5] = f2bf(y.y); v[6] = f2bf(y.z); v[7] = f2bf(y.w);
    *(us8*)(out + i) = v;
  }
}

// ---------------- prep: pack Wx [K][4096] f32 -> [K/8][4096 packed][8] bf16 ----------------
__global__ void pack_wx_kernel(const float* __restrict__ w, unsigned short* __restrict__ out, int total) {
  int t = blockIdx.x * blockDim.x + threadIdx.x;
  if (t >= total) return;
  int kb = t >> 12, n = t & 4095;
  int oc = orig_col3(n);
  us8 v;
#pragma unroll
  for (int ki = 0; ki < 8; ki++) v[ki] = f2bf(w[(size_t)(kb * 8 + ki) * G_ + oc]);
  *(us8*)(out + (size_t)t * 8) = v;
}

// ---------------- prep: pack Wh into scan B-fragments (ksl x nh wave split) ----------------
__global__ void pack_wh4_kernel(const float* __restrict__ w, unsigned short* __restrict__ out) {
  int t = blockIdx.x * blockDim.x + threadIdx.x;   // 524288 total
  int lane = t & 63;
  int nt  = (t >> 6) & 3;
  int ks  = (t >> 8) & 7;
  int ksl = (t >> 11) & 3;
  int nh  = (t >> 13) & 1;
  int s   = t >> 14;
  int k0 = ksl * 256 + ks * 32 + (lane >> 4) * 8;
  int oc = orig_col3(s * 128 + nh * 64 + nt * 16 + (lane & 15));
  us8 v;
#pragma unroll
  for (int i = 0; i < 8; i++) v[i] = f2bf(w[(size_t)(k0 + i) * G_ + oc]);
  *(us8*)(out + (size_t)t * 8) = v;
}

// ---------------- x_proj: gather(emb) @ Wx + b -> bf16 [TC*B][G packed] ----------------
#define XP_BM 128
#define XP_BN 128
#define XP_KC 64
__global__ __launch_bounds__(256, 2) void xproj_kernel(
    const int* __restrict__ sent, const unsigned short* __restrict__ embb,
    const unsigned short* __restrict__ wxp, const float* __restrict__ bias,
    unsigned short* __restrict__ xp, int t0)
{
  __shared__ __align__(16) unsigned short sA[2][XP_BM * XP_KC];
  __shared__ __align__(16) unsigned short sB[2][XP_KC * XP_BN];
  __shared__ int tok[XP_BM];

  const int tid = threadIdx.x;
  const int lane = tid & 63;
  const int wid = tid >> 6;
  const int m0 = blockIdx.x * XP_BM;
  const int n0 = blockIdx.y * XP_BN;

  if (tid < XP_BM) {
    int row = m0 + tid;
    int tl = row >> 8, b = row & 255;
    tok[tid] = sent[b * T_ + t0 + tl];
  }
  __syncthreads();

  auto stageA = [&](int bf, int kc) {
#pragma unroll
    for (int ii = 0; ii < 4; ii++) {
      int i = wid * 4 + ii;
      int m = i * 8 + (lane >> 3);
      int cl = lane & 7;
      gload16(embb + (size_t)tok[m] * E_ + kc + ((cl ^ (m & 7)) << 3), &sA[bf][i * 512]);
    }
  };
  auto stageB = [&](int bf, int kc) {
    int kb0 = kc >> 3;
#pragma unroll
    for (int jj = 0; jj < 4; jj++) {
      int j = wid * 4 + jj;
      int r = j >> 1;
      int nl = ((j & 1) << 6) + lane;
      int n = nl ^ r;
      gload16(wxp + ((size_t)(kb0 + r) * G_ + n0 + n) * 8, &sB[bf][j * 512]);
    }
  };

  f32x4 acc[4][4];
#pragma unroll
  for (int i = 0; i < 4; i++)
#pragma unroll
    for (int j = 0; j < 4; j++) acc[i][j] = f32x4{0.f, 0.f, 0.f, 0.f};

  const int wm = wid >> 1, wn = wid & 1;

  stageA(0, 0); stageB(0, 0);
  for (int it = 0; it < E_ / XP_KC; it++) {   // 8
    int bf = it & 1;
    __syncthreads();
    if (it < E_ / XP_KC - 1) { stageA(bf ^ 1, (it + 1) * XP_KC); stageB(bf ^ 1, (it + 1) * XP_KC); }
#pragma unroll
    for (int kk = 0; kk < 2; kk++) {
      int c = (kk << 2) + (lane >> 4);
      bf16x8 a[4], b[4];
#pragma unroll
      for (int ms = 0; ms < 4; ms++) {
        int m = (wm << 6) + (ms << 4) + (lane & 15);
        a[ms] = *(const bf16x8*)&sA[bf][m * 64 + ((c ^ (m & 7)) << 3)];
      }
#pragma unroll
      for (int ns = 0; ns < 4; ns++) {
        int n = (wn << 6) + (ns << 4) + (lane & 15);
        b[ns] = *(const bf16x8*)&sB[bf][((c << 7) + (n ^ c)) << 3];
      }
#pragma unroll
      for (int ms = 0; ms < 4; ms++)
#pragma unroll
        for (int ns = 0; ns < 4; ns++)
          acc[ms][ns] = __builtin_amdgcn_mfma_f32_16x16x32_bf16(a[ms], b[ns], acc[ms][ns], 0, 0, 0);
    }
  }

#pragma unroll
  for (int ns = 0; ns < 4; ns++) {
    int col = n0 + (wn << 6) + (ns << 4) + (lane & 15);
    float bv = bias[orig_col3(col)];
#pragma unroll
    for (int ms = 0; ms < 4; ms++) {
      int rbase = m0 + (wm << 6) + (ms << 4) + ((lane >> 4) << 2);
#pragma unroll
      for (int rr = 0; rr < 4; rr++)
        xp[(size_t)(rbase + rr) * G_ + col] = f2bf(acc[ms][ns][rr] + bv);
    }
  }
}

// ---------------- persistent scan v10: R6 structure + per-wave arrival (no B3) ----------------
// grid 256: block b -> group g=b&7 (rows g*32..+32), slot s=b>>3 (u-cols s*32..+32)
// 512 threads = 8 waves: wave w -> ksl=w&3 (K-slice of 256), nh=w>>2 (64-col N-half)
__global__ __launch_bounds__(512, 2) void scan_kernel(
    const unsigned short* __restrict__ xpc,   // [TC][256][4096 packed] bf16 (bias incl.)
    const unsigned short* __restrict__ whp4,  // packed Wh B-fragments
    unsigned short* __restrict__ hbuf,        // [2][256][1024] bf16
    float* __restrict__ cst,                  // [256][1024] f32
    int* __restrict__ flags,                  // [NG][32] ints, one 128B line per group
    int t0)
{
  __shared__ __align__(16) unsigned short sA[32 * 1024];   // 64KB h rows, swizzled 16B slots
  __shared__ float sEx[4][32][131];                         // 67KB K-slice partials (pad 131)
  __shared__ int larr;                                      // per-block wave-arrival counter

  const int tid = threadIdx.x, lane = tid & 63, w = tid >> 6;
  const int ksl = w & 3, nh = w >> 2;
  const int g = (int)blockIdx.x & 7, s = (int)blockIdx.x >> 3;
  const int m0g = g * 32, u0 = s * 32;
  const int hi = lane >> 4, lo = lane & 15;
  const int rx = lane & 7;

  // ---- Wh B-fragments in registers ----
  bf16x8 wh[8][4];
  {
    const bf16x8* wb = (const bf16x8*)whp4 + ((((size_t)s * 2 + nh) * 4 + ksl) * 32) * 64;
#pragma unroll
    for (int ks = 0; ks < 8; ks++)
#pragma unroll
      for (int nt = 0; nt < 4; nt++)
        wh[ks][nt] = wb[(ks * 4 + nt) * 64 + lane];
  }

  // ---- c-state in registers (2 elems per thread) ----
  const int r_e = tid >> 4, ue = (tid & 15) * 2;
  const size_t ci = (size_t)(m0g + r_e) * U_ + u0 + ue;
  float c0v = cst[ci], c1v = cst[ci + 1];

  if (tid == 0) larr = 0;
  __syncthreads();

  for (int ts = 0; ts < TC_; ts++) {
    const int t = t0 + ts;

    // ---- xpc prefetch (independent of h; retires during poll/stage) ----
    const unsigned short* xb = xpc + ((size_t)ts * B_ + (m0g + r_e)) * G_ + s * 128;
    unsigned xiv = *(const unsigned*)(xb + ue);
    unsigned xfv = *(const unsigned*)(xb + 32 + ue);
    unsigned xgv = *(const unsigned*)(xb + 64 + ue);
    unsigned xov = *(const unsigned*)(xb + 96 + ue);

    // ---- wait for h(t): all lanes poll the group's 32-flag line (agent/MALL scope) ----
    if (t > 0) {
      const int* fp = flags + g * 32 + (lane & 31);
      int v, it = 0;
      do { v = __hip_atomic_load(fp, __ATOMIC_RELAXED, __HIP_MEMORY_SCOPE_AGENT); }
      while (__any(v < t) && ++it < (1 << 16));   // cap: fail-visible, never 600s-hang
    }

    // ---- stage h rows [m0g,+32) x 1024 into sA (DMA, pre-swizzled source) ----
    const unsigned short* hsrc = hbuf + (size_t)(t & 1) * (B_ * U_) + (size_t)m0g * U_;
#pragma unroll
    for (int jj = 0; jj < 8; jj++) {
      int j = w * 8 + jj;                 // 64 issues, 1KB each
      int r = j >> 1, k2 = j & 1;
      gload16c(hsrc + (size_t)r * U_ + (((k2 << 6) | (lane ^ (r & 7))) << 3),
               &sA[r * 1024 + k2 * 512]);
    }
    __syncthreads();                      // B1: sA ready (barrier drains vmcnt)

    // ---- GEMM: [32 rows] x [64-col N-half] over K-slice 256 ----
    f32x4 acc[2][4];
#pragma unroll
    for (int mt = 0; mt < 2; mt++)
#pragma unroll
      for (int nt = 0; nt < 4; nt++) acc[mt][nt] = f32x4{0.f, 0.f, 0.f, 0.f};
    const char* abase0 = (const char*)sA + (size_t)lo * 2048;
    const char* abase1 = abase0 + 16 * 2048;
#pragma unroll
    for (int ks = 0; ks < 8; ks++) {
      int c = ksl * 32 + ks * 4 + hi;     // 16B slot within full K
      int off = (c ^ rx) << 4;
      bf16x8 a0 = *(const bf16x8*)(abase0 + off);
      bf16x8 a1 = *(const bf16x8*)(abase1 + off);
#pragma unroll
      for (int nt = 0; nt < 4; nt++) {
        acc[0][nt] = __builtin_amdgcn_mfma_f32_16x16x32_bf16(a0, wh[ks][nt], acc[0][nt], 0, 0, 0);
        acc[1][nt] = __builtin_amdgcn_mfma_f32_16x16x32_bf16(a1, wh[ks][nt], acc[1][nt], 0, 0, 0);
      }
    }

    // ---- write K-slice partials (pad 131: ~2-way, free) ----
#pragma unroll
    for (int mt = 0; mt < 2; mt++)
#pragma unroll
      for (int nt = 0; nt < 4; nt++)
#pragma unroll
        for (int rr = 0; rr < 4; rr++)
          sEx[ksl][mt * 16 + hi * 4 + rr][nh * 64 + nt * 16 + lo] = acc[mt][nt][rr];
    __syncthreads();                      // B2: partials ready

    // ---- elementwise: thread -> (row r_e, u = ue, ue+1); sum 4 K-slices ----
    {
      float cn[2]; unsigned hv = 0;
#pragma unroll
      for (int j = 0; j < 2; j++) {
        int u = ue + j;
        float gi = sEx[0][r_e][u]      + sEx[1][r_e][u]      + sEx[2][r_e][u]      + sEx[3][r_e][u]      + bf2f((unsigned short)(j ? (xiv >> 16) : xiv));
        float gf = sEx[0][r_e][32 + u] + sEx[1][r_e][32 + u] + sEx[2][r_e][32 + u] + sEx[3][r_e][32 + u] + bf2f((unsigned short)(j ? (xfv >> 16) : xfv));
        float gg = sEx[0][r_e][64 + u] + sEx[1][r_e][64 + u] + sEx[2][r_e][64 + u] + sEx[3][r_e][64 + u] + bf2f((unsigned short)(j ? (xgv >> 16) : xgv));
        float go = sEx[0][r_e][96 + u] + sEx[1][r_e][96 + u] + sEx[2][r_e][96 + u] + sEx[3][r_e][96 + u] + bf2f((unsigned short)(j ? (xov >> 16) : xov));
        float co = j ? c1v : c0v;
        float cv = sigm_(gf) * co + sigm_(gi) * tanh_(gg);
        cn[j] = cv;
        hv |= (unsigned)f2bf(sigm_(go) * tanh_(cv)) << (16 * j);
      }
      c0v = cn[0]; c1v = cn[1];
      *(unsigned*)(hbuf + (size_t)((t + 1) & 1) * (B_ * U_) + ci) = hv;  // plain store
    }

    // ---- per-wave arrival (replaces B3): drain own h-stores, LDS-arrive;
    //      the 8th wave of this block publishes the group flag (agent scope) ----
    asm volatile("s_waitcnt vmcnt(0)" ::: "memory");
    if (lane == 0) {
      int old = __hip_atomic_fetch_add(&larr, 1, __ATOMIC_RELAXED, __HIP_MEMORY_SCOPE_WORKGROUP);
      if (old == 8 * ts + 7)
        __hip_atomic_store(flags + g * 32 + s, t + 1, __ATOMIC_RELAXED, __HIP_MEMORY_SCOPE_AGENT);
    }
    // no block barrier here: sA/sEx reuse at step ts+1 is ordered by the poll
    // (own block's 8 waves must all have arrived before any group flag reaches t+1)
  }

  cst[ci] = c0v; cst[ci + 1] = c1v;   // plain: kernel-boundary release covers next dispatch
}

// ---------------- head: sigmoid((h@W1+b1)@W2+b2) ----------------
__global__ __launch_bounds__(256) void dense_kernel(
    const unsigned short* __restrict__ h, const float* __restrict__ W1, const float* __restrict__ b1,
    const float* __restrict__ W2, const float* __restrict__ b2, float* __restrict__ out)
{
  int tid = threadIdx.x, j = tid & 63, kq = tid >> 6;
  const unsigned short* hr = h + (size_t)blockIdx.x * U_;
  float s = 0.f;
#pragma unroll 8
  for (int k = kq * 256; k < kq * 256 + 256; k++) s += bf2f(hr[k]) * W1[k * 64 + j];
  __shared__ float red[4][64];
  red[kq][j] = s;
  __syncthreads();
  if (tid < 64) {
    float hid = red[0][j] + red[1][j] + red[2][j] + red[3][j] + b1[j];
    float p = hid * W2[j];
#pragma unroll
    for (int off = 32; off; off >>= 1) p += __shfl_down(p, off, 64);
    if (j == 0) out[blockIdx.x] = 1.f / (1.f + __expf(-(p + b2[0])));
  }
}

extern "C" void kernel_launch(void* const* d_in, const int* in_sizes, int n_in,
                              void* d_out, int out_size, void* d_ws, size_t ws_size,
                              hipStream_t stream) {
  const int*   sent = (const int*)d_in[0];
  const float* emb  = (const float*)d_in[1];
  const float* Wx   = (const float*)d_in[2];
  const float* Wh   = (const float*)d_in[3];
  const float* bias = (const float*)d_in[4];
  const float* W1   = (const float*)d_in[5];
  const float* b1   = (const float*)d_in[6];
  const float* W2   = (const float*)d_in[7];
  const float* b2   = (const float*)d_in[8];
  float* out = (float*)d_out;

  char* ws = (char*)d_ws;
  size_t off = 0;
  auto alloc = [&](size_t bytes) { void* p = ws + off; off += (bytes + 255) & ~(size_t)255; return p; };
  unsigned short* embb = (unsigned short*)alloc((size_t)V_ * E_ * 2);       // 51.2 MB
  unsigned short* wxp  = (unsigned short*)alloc((size_t)E_ * G_ * 2);       // 4.2 MB
  unsigned short* whp4 = (unsigned short*)alloc((size_t)U_ * G_ * 2);       // 8.4 MB
  unsigned short* xpc  = (unsigned short*)alloc((size_t)TC_ * B_ * G_ * 2); // 67 MB
  unsigned short* hbuf = (unsigned short*)alloc((size_t)2 * B_ * U_ * 2);   // 1 MB
  float*          cst  = (float*)alloc((size_t)B_ * U_ * 4);                // 1 MB
  int*            flg  = (int*)alloc((size_t)NG_ * 32 * 4);                 // 1 KB

  // prep
  hipLaunchKernelGGL(cvt_bf16_kernel, dim3(12500), dim3(256), 0, stream, emb, embb, (long)V_ * E_);
  hipLaunchKernelGGL(pack_wx_kernel, dim3((E_ / 8) * G_ / 256), dim3(256), 0, stream, Wx, wxp, (E_ / 8) * G_);
  hipLaunchKernelGGL(pack_wh4_kernel, dim3(2048), dim3(256), 0, stream, Wh, whp4);
  hipMemsetAsync(hbuf, 0, (size_t)B_ * U_ * 2, stream);            // h(0) = 0 (parity 0)
  hipMemsetAsync(cst, 0, (size_t)B_ * U_ * 4, stream);             // c(0) = 0
  hipMemsetAsync(flg, 0, (size_t)NG_ * 32 * 4, stream);            // flags = 0 every replay

  for (int ch = 0; ch < NCH_; ch++) {
    hipLaunchKernelGGL(xproj_kernel, dim3(TC_ * B_ / XP_BM, G_ / XP_BN), dim3(256), 0, stream,
                       sent, embb, wxp, bias, xpc, ch * TC_);
    hipLaunchKernelGGL(scan_kernel, dim3(NG_ * NS_), dim3(512), 0, stream,
                       xpc, whp4, hbuf, cst, flg, ch * TC_);
  }
  hipLaunchKernelGGL(dense_kernel, dim3(B_), dim3(256), 0, stream,
                     hbuf /* h(256) lands in parity 0 */, W1, b1, W2, b2, out);
}

// Round 11
// 1507.825 us; speedup vs baseline: 1.4580x; 1.4580x over previous
//
#include <hip/hip_runtime.h>

#define B_ 256
#define T_ 256
#define E_ 512
#define U_ 1024
#define G_ 4096   // 4*U
#define V_ 50000
#define TC_ 32    // timesteps per x_proj chunk
#define NCH_ 8    // T_/TC_
#define NG_ 8     // scan groups (one per XCD under %8 round-robin)
#define NS_ 32    // slots (blocks) per group

typedef __bf16 bf16x8 __attribute__((ext_vector_type(8)));
typedef float f32x4 __attribute__((ext_vector_type(4)));
typedef unsigned short us8 __attribute__((ext_vector_type(8)));

__device__ __forceinline__ unsigned short f2bf(float f) {
  union { float f; unsigned u; } v; v.f = f;
  unsigned u = v.u;
  u = (u + 0x7FFFu + ((u >> 16) & 1u)) >> 16;   // RNE
  return (unsigned short)u;
}
__device__ __forceinline__ float bf2f(unsigned short h) {
  union { unsigned u; float f; } v; v.u = ((unsigned)h) << 16;
  return v.f;
}
__device__ __forceinline__ float sigm_(float x) { return 1.f / (1.f + __expf(-x)); }
__device__ __forceinline__ float tanh_(float x) { return 2.f / (1.f + __expf(-2.f * x)) - 1.f; }

__device__ __forceinline__ void gload16(const void* g, void* l) {
  __builtin_amdgcn_global_load_lds((const __attribute__((address_space(1))) void*)g,
                                   (__attribute__((address_space(3))) void*)l, 16, 0, 0);
}
// sc0 variant: L1-bypass, served/coherent at the XCD's L2 (R6-proven)
__device__ __forceinline__ void gload16c(const void* g, void* l) {
  __builtin_amdgcn_global_load_lds((const __attribute__((address_space(1))) void*)g,
                                   (__attribute__((address_space(3))) void*)l, 16, 0, 1);
}

// packed column p = s*128 + gg*32 + ul  ->  original gate column gg*1024 + s*32 + ul
__device__ __forceinline__ int orig_col3(int p) {
  return (((p >> 5) & 3) << 10) + ((p >> 7) << 5) + (p & 31);
}

// ---------------- prep: f32 -> bf16 (row-major) ----------------
__global__ void cvt_bf16_kernel(const float* __restrict__ in, unsigned short* __restrict__ out, long n) {
  long i = (((long)blockIdx.x * blockDim.x) + threadIdx.x) << 3;
  long stride = ((long)gridDim.x * blockDim.x) << 3;
  for (; i < n; i += stride) {
    float4 x = *(const float4*)(in + i);
    float4 y = *(const float4*)(in + i + 4);
    us8 v;
    v[0] = f2bf(x.x); v[1] = f2bf(x.y); v[2] = f2bf(x.z); v[3] = f2bf(x.w);
    v[4] = f2bf(y.x); v[5] = f2bf(y.y); v[6] = f2bf(y.z); v[7] = f2bf(y.w);
    *(us8*)(out + i) = v;
  }
}

// ---------------- prep: pack Wx [K][4096] f32 -> [K/8][4096 packed][8] bf16 ----------------
__global__ void pack_wx_kernel(const float* __restrict__ w, unsigned short* __restrict__ out, int total) {
  int t = blockIdx.x * blockDim.x + threadIdx.x;
  if (t >= total) return;
  int kb = t >> 12, n = t & 4095;
  int oc = orig_col3(n);
  us8 v;
#pragma unroll
  for (int ki = 0; ki < 8; ki++) v[ki] = f2bf(w[(size_t)(kb * 8 + ki) * G_ + oc]);
  *(us8*)(out + (size_t)t * 8) = v;
}

// ---------------- prep: pack Wh into scan B-fragments (ksl x nh wave split) ----------------
// flat t bits (low->high): [lane:6][nt:2][ks:3][ksl:2][nh:1][s:5]
// elem i = Wh[ksl*256 + ks*32 + (lane>>4)*8 + i][orig_col3(s*128 + nh*64 + nt*16 + (lane&15))]
__global__ void pack_wh4_kernel(const float* __restrict__ w, unsigned short* __restrict__ out) {
  int t = blockIdx.x * blockDim.x + threadIdx.x;   // 524288 total
  int lane = t & 63;
  int nt  = (t >> 6) & 3;
  int ks  = (t >> 8) & 7;
  int ksl = (t >> 11) & 3;
  int nh  = (t >> 13) & 1;
  int s   = t >> 14;
  int k0 = ksl * 256 + ks * 32 + (lane >> 4) * 8;
  int oc = orig_col3(s * 128 + nh * 64 + nt * 16 + (lane & 15));
  us8 v;
#pragma unroll
  for (int i = 0; i < 8; i++) v[i] = f2bf(w[(size_t)(k0 + i) * G_ + oc]);
  *(us8*)(out + (size_t)t * 8) = v;
}

// ---------------- x_proj: gather(emb) @ Wx + b -> bf16 [TC*B][G packed] ----------------
#define XP_BM 128
#define XP_BN 128
#define XP_KC 64
__global__ __launch_bounds__(256, 2) void xproj_kernel(
    const int* __restrict__ sent, const unsigned short* __restrict__ embb,
    const unsigned short* __restrict__ wxp, const float* __restrict__ bias,
    unsigned short* __restrict__ xp, int t0)
{
  __shared__ __align__(16) unsigned short sA[2][XP_BM * XP_KC];
  __shared__ __align__(16) unsigned short sB[2][XP_KC * XP_BN];
  __shared__ int tok[XP_BM];

  const int tid = threadIdx.x;
  const int lane = tid & 63;
  const int wid = tid >> 6;
  const int m0 = blockIdx.x * XP_BM;
  const int n0 = blockIdx.y * XP_BN;

  if (tid < XP_BM) {
    int row = m0 + tid;
    int tl = row >> 8, b = row & 255;
    tok[tid] = sent[b * T_ + t0 + tl];
  }
  __syncthreads();

  auto stageA = [&](int bf, int kc) {
#pragma unroll
    for (int ii = 0; ii < 4; ii++) {
      int i = wid * 4 + ii;
      int m = i * 8 + (lane >> 3);
      int cl = lane & 7;
      gload16(embb + (size_t)tok[m] * E_ + kc + ((cl ^ (m & 7)) << 3), &sA[bf][i * 512]);
    }
  };
  auto stageB = [&](int bf, int kc) {
    int kb0 = kc >> 3;
#pragma unroll
    for (int jj = 0; jj < 4; jj++) {
      int j = wid * 4 + jj;
      int r = j >> 1;
      int nl = ((j & 1) << 6) + lane;
      int n = nl ^ r;
      gload16(wxp + ((size_t)(kb0 + r) * G_ + n0 + n) * 8, &sB[bf][j * 512]);
    }
  };

  f32x4 acc[4][4];
#pragma unroll
  for (int i = 0; i < 4; i++)
#pragma unroll
    for (int j = 0; j < 4; j++) acc[i][j] = f32x4{0.f, 0.f, 0.f, 0.f};

  const int wm = wid >> 1, wn = wid & 1;

  stageA(0, 0); stageB(0, 0);
  for (int it = 0; it < E_ / XP_KC; it++) {   // 8
    int bf = it & 1;
    __syncthreads();
    if (it < E_ / XP_KC - 1) { stageA(bf ^ 1, (it + 1) * XP_KC); stageB(bf ^ 1, (it + 1) * XP_KC); }
#pragma unroll
    for (int kk = 0; kk < 2; kk++) {
      int c = (kk << 2) + (lane >> 4);
      bf16x8 a[4], b[4];
#pragma unroll
      for (int ms = 0; ms < 4; ms++) {
        int m = (wm << 6) + (ms << 4) + (lane & 15);
        a[ms] = *(const bf16x8*)&sA[bf][m * 64 + ((c ^ (m & 7)) << 3)];
      }
#pragma unroll
      for (int ns = 0; ns < 4; ns++) {
        int n = (wn << 6) + (ns << 4) + (lane & 15);
        b[ns] = *(const bf16x8*)&sB[bf][((c << 7) + (n ^ c)) << 3];
      }
#pragma unroll
      for (int ms = 0; ms < 4; ms++)
#pragma unroll
        for (int ns = 0; ns < 4; ns++)
          acc[ms][ns] = __builtin_amdgcn_mfma_f32_16x16x32_bf16(a[ms], b[ns], acc[ms][ns], 0, 0, 0);
    }
  }

#pragma unroll
  for (int ns = 0; ns < 4; ns++) {
    int col = n0 + (wn << 6) + (ns << 4) + (lane & 15);
    float bv = bias[orig_col3(col)];
#pragma unroll
    for (int ms = 0; ms < 4; ms++) {
      int rbase = m0 + (wm << 6) + (ms << 4) + ((lane >> 4) << 2);
#pragma unroll
      for (int rr = 0; rr < 4; rr++)
        xp[(size_t)(rbase + rr) * G_ + col] = f2bf(acc[ms][ns][rr] + bv);
    }
  }
}

// ---------------- persistent scan v11: R6 structure + single-wave poller ----------------
// grid 256: block b -> group g=b&7 (rows g*32..+32, XCD-local), slot s=b>>3 (u-cols s*32..+32)
// 512 threads = 8 waves: wave w -> ksl=w&3 (K-slice of 256), nh=w>>2 (64-col N-half)
__global__ __launch_bounds__(512, 2) void scan_kernel(
    const unsigned short* __restrict__ xpc,   // [TC][256][4096 packed] bf16 (bias incl.)
    const unsigned short* __restrict__ whp4,  // packed Wh B-fragments
    unsigned short* __restrict__ hbuf,        // [2][256][1024] bf16
    float* __restrict__ cst,                  // [256][1024] f32
    int* __restrict__ flags,                  // [NG][32] ints, one 128B line per group
    int t0)
{
  __shared__ __align__(16) unsigned short sA[32 * 1024];   // 64KB h rows, swizzled 16B slots
  __shared__ float sEx[4][32][131];                         // 67KB K-slice partials (pad 131)
  __shared__ int sready;                                    // step broadcast

  const int tid = threadIdx.x, lane = tid & 63, w = tid >> 6;
  const int ksl = w & 3, nh = w >> 2;
  const int g = (int)blockIdx.x & 7, s = (int)blockIdx.x >> 3;
  const int m0g = g * 32, u0 = s * 32;
  const int rx = lane & 7, hi = lane >> 4, lo = lane & 15;

  // ---- Wh B-fragments in registers: 32 x bf16x8 = 128 regs ----
  bf16x8 wh[8][4];
  {
    const bf16x8* wb = (const bf16x8*)whp4 + ((((size_t)s * 2 + nh) * 4 + ksl) * 32) * 64;
#pragma unroll
    for (int ks = 0; ks < 8; ks++)
#pragma unroll
      for (int nt = 0; nt < 4; nt++)
        wh[ks][nt] = wb[(ks * 4 + nt) * 64 + lane];
  }

  // ---- c-state in registers (2 elems per thread) ----
  const int r_e = tid >> 4, ue = (tid & 15) * 2;
  const size_t ci = (size_t)(m0g + r_e) * U_ + u0 + ue;
  float c0v = cst[ci], c1v = cst[ci + 1];

  if (tid == 0) sready = 0;
  __syncthreads();

  for (int ts = 0; ts < TC_; ts++) {
    const int t = t0 + ts;

    // ---- xpc prefetch (independent of h; drains during poll/stage) ----
    const unsigned short* xb = xpc + ((size_t)ts * B_ + (m0g + r_e)) * G_ + s * 128;
    unsigned xiv = *(const unsigned*)(xb + ue);
    unsigned xfv = *(const unsigned*)(xb + 32 + ue);
    unsigned xgv = *(const unsigned*)(xb + 64 + ue);
    unsigned xov = *(const unsigned*)(xb + 96 + ue);

    // ---- wait for h(t): wave 0 polls the 32-flag line; others spin on LDS broadcast ----
    if (t > 0) {
      if (w == 0) {
        const int* fp = flags + g * 32 + (lane & 31);
        int v, it = 0;
        do { v = __hip_atomic_load(fp, __ATOMIC_RELAXED, __HIP_MEMORY_SCOPE_AGENT); }
        while (__any(v < t) && ++it < (1 << 20));   // cap: fail-visible, never 600s-hang
        if (lane == 0)
          __hip_atomic_store(&sready, t, __ATOMIC_RELAXED, __HIP_MEMORY_SCOPE_WORKGROUP);
      } else {
        int it = 0;
        while (__hip_atomic_load(&sready, __ATOMIC_RELAXED, __HIP_MEMORY_SCOPE_WORKGROUP) < t
               && ++it < (1 << 22)) {}
      }
    }

    // ---- stage h rows [m0g,+32) x 1024 into sA (sc0 L2 DMA, pre-swizzled source) ----
    const unsigned short* hsrc = hbuf + (size_t)(t & 1) * (B_ * U_) + (size_t)m0g * U_;
#pragma unroll
    for (int jj = 0; jj < 8; jj++) {
      int j = w * 8 + jj;                 // 64 issues, 1KB each
      int r = j >> 1, k2 = j & 1;
      gload16c(hsrc + (size_t)r * U_ + (((k2 << 6) | (lane ^ (r & 7))) << 3),
               &sA[r * 1024 + k2 * 512]);
    }
    __syncthreads();                      // B1: sA ready (barrier drains vmcnt)

    // ---- GEMM: [32 rows] x [64-col N-half] over K-slice 256 ----
    f32x4 acc[2][4];
#pragma unroll
    for (int mt = 0; mt < 2; mt++)
#pragma unroll
      for (int nt = 0; nt < 4; nt++) acc[mt][nt] = f32x4{0.f, 0.f, 0.f, 0.f};
    const char* abase0 = (const char*)sA + (size_t)lo * 2048;
    const char* abase1 = abase0 + 16 * 2048;
#pragma unroll
    for (int ks = 0; ks < 8; ks++) {
      int c = ksl * 32 + ks * 4 + hi;     // 16B slot within full K
      int off = (c ^ rx) << 4;
      bf16x8 a0 = *(const bf16x8*)(abase0 + off);
      bf16x8 a1 = *(const bf16x8*)(abase1 + off);
#pragma unroll
      for (int nt = 0; nt < 4; nt++) {
        acc[0][nt] = __builtin_amdgcn_mfma_f32_16x16x32_bf16(a0, wh[ks][nt], acc[0][nt], 0, 0, 0);
        acc[1][nt] = __builtin_amdgcn_mfma_f32_16x16x32_bf16(a1, wh[ks][nt], acc[1][nt], 0, 0, 0);
      }
    }

    // ---- write K-slice partials (pad 131: ~2-way, free) ----
#pragma unroll
    for (int mt = 0; mt < 2; mt++)
#pragma unroll
      for (int nt = 0; nt < 4; nt++)
#pragma unroll
        for (int rr = 0; rr < 4; rr++)
          sEx[ksl][mt * 16 + hi * 4 + rr][nh * 64 + nt * 16 + lo] = acc[mt][nt][rr];
    __syncthreads();                      // B2: partials ready

    // ---- elementwise: thread -> (row r_e, u = ue, ue+1); sum 4 K-slices ----
    {
      float cn[2]; unsigned hv = 0;
#pragma unroll
      for (int j = 0; j < 2; j++) {
        int u = ue + j;
        float gi = sEx[0][r_e][u]      + sEx[1][r_e][u]      + sEx[2][r_e][u]      + sEx[3][r_e][u]      + bf2f((unsigned short)(j ? (xiv >> 16) : xiv));
        float gf = sEx[0][r_e][32 + u] + sEx[1][r_e][32 + u] + sEx[2][r_e][32 + u] + sEx[3][r_e][32 + u] + bf2f((unsigned short)(j ? (xfv >> 16) : xfv));
        float gg = sEx[0][r_e][64 + u] + sEx[1][r_e][64 + u] + sEx[2][r_e][64 + u] + sEx[3][r_e][64 + u] + bf2f((unsigned short)(j ? (xgv >> 16) : xgv));
        float go = sEx[0][r_e][96 + u] + sEx[1][r_e][96 + u] + sEx[2][r_e][96 + u] + sEx[3][r_e][96 + u] + bf2f((unsigned short)(j ? (xov >> 16) : xov));
        float co = j ? c1v : c0v;
        float cv = sigm_(gf) * co + sigm_(gi) * tanh_(gg);
        cn[j] = cv;
        hv |= (unsigned)f2bf(sigm_(go) * tanh_(cv)) << (16 * j);
      }
      c0v = cn[0]; c1v = cn[1];
      *(unsigned*)(hbuf + (size_t)((t + 1) & 1) * (B_ * U_) + ci) = hv;  // plain -> XCD L2
    }
    __syncthreads();                      // B3: h stores drained (vmcnt 0 at barrier)
    if (tid == 0)
      __hip_atomic_store(flags + g * 32 + s, t + 1, __ATOMIC_RELAXED, __HIP_MEMORY_SCOPE_AGENT);
  }

  cst[ci] = c0v; cst[ci + 1] = c1v;   // plain: kernel-boundary release covers next dispatch
}

// ---------------- head: sigmoid((h@W1+b1)@W2+b2) ----------------
__global__ __launch_bounds__(256) void dense_kernel(
    const unsigned short* __restrict__ h, const float* __restrict__ W1, const float* __restrict__ b1,
    const float* __restrict__ W2, const float* __restrict__ b2, float* __restrict__ out)
{
  int tid = threadIdx.x, j = tid & 63, kq = tid >> 6;
  const unsigned short* hr = h + (size_t)blockIdx.x * U_;
  float s = 0.f;
#pragma unroll 8
  for (int k = kq * 256; k < kq * 256 + 256; k++) s += bf2f(hr[k]) * W1[k * 64 + j];
  __shared__ float red[4][64];
  red[kq][j] = s;
  __syncthreads();
  if (tid < 64) {
    float hid = red[0][j] + red[1][j] + red[2][j] + red[3][j] + b1[j];
    float p = hid * W2[j];
#pragma unroll
    for (int off = 32; off; off >>= 1) p += __shfl_down(p, off, 64);
    if (j == 0) out[blockIdx.x] = 1.f / (1.f + __expf(-(p + b2[0])));
  }
}

extern "C" void kernel_launch(void* const* d_in, const int* in_sizes, int n_in,
                              void* d_out, int out_size, void* d_ws, size_t ws_size,
                              hipStream_t stream) {
  const int*   sent = (const int*)d_in[0];
  const float* emb  = (const float*)d_in[1];
  const float* Wx   = (const float*)d_in[2];
  const float* Wh   = (const float*)d_in[3];
  const float* bias = (const float*)d_in[4];
  const float* W1   = (const float*)d_in[5];
  const float* b1   = (const float*)d_in[6];
  const float* W2   = (const float*)d_in[7];
  const float* b2   = (const float*)d_in[8];
  float* out = (float*)d_out;

  char* ws = (char*)d_ws;
  size_t off = 0;
  auto alloc = [&](size_t bytes) { void* p = ws + off; off += (bytes + 255) & ~(size_t)255; return p; };
  unsigned short* embb = (unsigned short*)alloc((size_t)V_ * E_ * 2);       // 51.2 MB
  unsigned short* wxp  = (unsigned short*)alloc((size_t)E_ * G_ * 2);       // 4.2 MB
  unsigned short* whp4 = (unsigned short*)alloc((size_t)U_ * G_ * 2);       // 8.4 MB
  unsigned short* xpc  = (unsigned short*)alloc((size_t)TC_ * B_ * G_ * 2); // 67 MB
  unsigned short* hbuf = (unsigned short*)alloc((size_t)2 * B_ * U_ * 2);   // 1 MB
  float*          cst  = (float*)alloc((size_t)B_ * U_ * 4);                // 1 MB
  int*            flg  = (int*)alloc((size_t)NG_ * 32 * 4);                 // 1 KB

  // prep
  hipLaunchKernelGGL(cvt_bf16_kernel, dim3(12500), dim3(256), 0, stream, emb, embb, (long)V_ * E_);
  hipLaunchKernelGGL(pack_wx_kernel, dim3((E_ / 8) * G_ / 256), dim3(256), 0, stream, Wx, wxp, (E_ / 8) * G_);
  hipLaunchKernelGGL(pack_wh4_kernel, dim3(2048), dim3(256), 0, stream, Wh, whp4);
  hipMemsetAsync(hbuf, 0, (size_t)B_ * U_ * 2, stream);            // h(0) = 0 (parity 0)
  hipMemsetAsync(cst, 0, (size_t)B_ * U_ * 4, stream);             // c(0) = 0
  hipMemsetAsync(flg, 0, (size_t)NG_ * 32 * 4, stream);            // flags = 0 every replay

  for (int ch = 0; ch < NCH_; ch++) {
    hipLaunchKernelGGL(xproj_kernel, dim3(TC_ * B_ / XP_BM, G_ / XP_BN), dim3(256), 0, stream,
                       sent, embb, wxp, bias, xpc, ch * TC_);
    hipLaunchKernelGGL(scan_kernel, dim3(NG_ * NS_), dim3(512), 0, stream,
                       xpc, whp4, hbuf, cst, flg, ch * TC_);
  }
  hipLaunchKernelGGL(dense_kernel, dim3(B_), dim3(256), 0, stream,
                     hbuf /* h(256) lands in parity 0 */, W1, b1, W2, b2, out);
}